// Round 4
// baseline (216.516 us; speedup 1.0000x reference)
//
#include <hip/hip_runtime.h>
#include <stdint.h>

typedef int i32x4 __attribute__((ext_vector_type(4)));

#define K_DIM 1024
#define BM 256
#define BN 256
#define BKK 64
#define NKT (K_DIM / BKK)   // 16

// ---------------- helpers ----------------
__device__ __forceinline__ int quant1(float v, float inv) {
  float t = rintf(v * inv);                 // round half-to-even, matches jnp.round
  t = fminf(fmaxf(t, -128.0f), 127.0f);     // clip(-n-1, n)
  return (int)t;
}

__device__ __forceinline__ void gld_lds16(const signed char* g, signed char* l) {
  typedef const __attribute__((address_space(1))) unsigned int* gp_t;
  typedef __attribute__((address_space(3))) unsigned int* lp_t;
  __builtin_amdgcn_global_load_lds((gp_t)(const void*)g, (lp_t)(void*)l, 16, 0, 0);
}

// ---------------- 1) global absmax over hs ----------------
__global__ void absmax_kernel(const float* __restrict__ x, unsigned int* __restrict__ amax,
                              long long n4) {
  long long i = (long long)blockIdx.x * blockDim.x + threadIdx.x;
  const long long stride = (long long)gridDim.x * blockDim.x;
  const float4* x4 = (const float4*)x;
  float m = 0.0f;
  for (; i < n4; i += stride) {
    float4 v = x4[i];
    m = fmaxf(m, fmaxf(fmaxf(fabsf(v.x), fabsf(v.y)), fmaxf(fabsf(v.z), fabsf(v.w))));
  }
#pragma unroll
  for (int off = 32; off > 0; off >>= 1) m = fmaxf(m, __shfl_down(m, off, 64));
  __shared__ float sm[4];
  const int lane = threadIdx.x & 63, wid = threadIdx.x >> 6;
  if (lane == 0) sm[wid] = m;
  __syncthreads();
  if (threadIdx.x == 0) {
    float b = fmaxf(fmaxf(sm[0], sm[1]), fmaxf(sm[2], sm[3]));
    atomicMax(amax, __float_as_uint(b));   // all values >= 0: uint order == float order
  }
}

// ---------------- 2) per-channel weight quant + bias ----------------
__global__ void wquant_kernel(const float* __restrict__ w, const float* __restrict__ bias,
                              const unsigned int* __restrict__ amax_u,
                              signed char* __restrict__ wq,
                              float* __restrict__ bscale, float* __restrict__ bint) {
  const int o = blockIdx.x;
  const int t = threadIdx.x;
  float4 v = ((const float4*)(w + (size_t)o * K_DIM))[t];
  float m = fmaxf(fmaxf(fabsf(v.x), fabsf(v.y)), fmaxf(fabsf(v.z), fabsf(v.w)));
#pragma unroll
  for (int off = 32; off > 0; off >>= 1) m = fmaxf(m, __shfl_down(m, off, 64));
  __shared__ float sm[4];
  __shared__ float s_scale;
  const int lane = t & 63, wid = t >> 6;
  if (lane == 0) sm[wid] = m;
  __syncthreads();
  if (t == 0) {
    float wm = fmaxf(fmaxf(sm[0], sm[1]), fmaxf(sm[2], sm[3]));
    float wsc = fmaxf(wm, 1e-8f) / 127.0f;
    float asc = fmaxf(__uint_as_float(*amax_u), 1e-8f) / 127.0f;
    float bsc = wsc * asc;
    bscale[o] = bsc;
    bint[o] = rintf(bias[o] / bsc);        // b_int kept as float (unclipped, like ref)
    s_scale = wsc;
  }
  __syncthreads();
  const float inv = 1.0f / s_scale;
  int q0 = quant1(v.x, inv), q1 = quant1(v.y, inv), q2 = quant1(v.z, inv), q3 = quant1(v.w, inv);
  unsigned int p = (unsigned)(q0 & 255) | ((unsigned)(q1 & 255) << 8) |
                   ((unsigned)(q2 & 255) << 16) | ((unsigned)(q3 & 255) << 24);
  ((unsigned int*)wq)[o * 256 + t] = p;
}

// ---------------- 3) activation quant ----------------
__global__ void aquant_kernel(const float* __restrict__ x, const unsigned int* __restrict__ amax_u,
                              unsigned int* __restrict__ q4, long long n4) {
  const float asc = fmaxf(__uint_as_float(*amax_u), 1e-8f) / 127.0f;
  const float inv = 1.0f / asc;
  long long i = (long long)blockIdx.x * blockDim.x + threadIdx.x;
  const long long stride = (long long)gridDim.x * blockDim.x;
  const float4* x4 = (const float4*)x;
  for (; i < n4; i += stride) {
    float4 v = x4[i];
    int q0 = quant1(v.x, inv), q1 = quant1(v.y, inv), q2 = quant1(v.z, inv), q3 = quant1(v.w, inv);
    q4[i] = (unsigned)(q0 & 255) | ((unsigned)(q1 & 255) << 8) |
            ((unsigned)(q2 & 255) << 16) | ((unsigned)(q3 & 255) << 24);
  }
}

// ---------------- 4) int8 GEMM, m201-style 8-phase 256x256 template ----------------
// A[M,K] int8 row-major (x_int), W[N,K] int8 row-major (w_int, B^T)
// out[M,N] f32 = ((int32)A.W^T + b_int[n]) * bscale[n]
//
// 512 thr = 8 waves (2M x 4N), wave tile 128x64, acc[8][4] i32x4.
// LDS: 4 buffers x (A 16KB + B 16KB) = 128KB dynamic, fragment-ordered:
//   frag f (16 rows x 64 k int8 = 1KB), lane l holds bytes [l*16, l*16+16)
//   = row (l&15), k (l>>4)*16.. -> gld_lds lane-linear, ds_read_b128 conflict-free.
// Per K-tile: 4 phases x 8 MFMA (16x16x64 i8), register-reuse ordering:
//   P0 reads af(M0..3)+bf(N0..1), P1 reads bf(N2..3), P2 reads af(M4..7), P3 none.
// Prefetch: tile t+3 issued at t.P0 (4 gld_lds/wave); wait for tile t+1 at t.P3
//   with counted vmcnt(8) (12 outstanding -> 8). Never drains to 0 mid-loop.
__global__ __launch_bounds__(512, 2) void gemm_kernel(
    const signed char* __restrict__ A, const signed char* __restrict__ W,
    const float* __restrict__ bscale, const float* __restrict__ bint,
    float* __restrict__ out, int M, int N, int K) {
  extern __shared__ __align__(16) signed char smem[];   // 131072 B
  signed char* Abase = smem;            // [4][16][1024]
  signed char* Bbase = smem + 65536;    // [4][16][1024]

  // bijective XCD swizzle (gridDim.x % 8 == 0)
  const int nwg = gridDim.x;
  const int orig = blockIdx.x;
  const int wgid = (orig & 7) * (nwg >> 3) + (orig >> 3);
  const int nbn = N / BN;
  const int bm = wgid / nbn;
  const int bn = wgid % nbn;
  const int m0 = bm * BM, n0 = bn * BN;

  const int tid = threadIdx.x;
  const int lane = tid & 63;
  const int wid = tid >> 6;          // 8 waves
  const int wr = wid >> 2;           // 2 wave-rows
  const int wc = wid & 3;            // 4 wave-cols

  const int fr = lane & 15;
  const int fk = (lane >> 4) << 4;

  // wave stages A-frags {wid, wid+8}, B-frags {wid, wid+8}
  const signed char* ga = A + (size_t)(m0 + wid * 16 + fr) * K + fk;
  const signed char* gb = W + (size_t)(n0 + wid * 16 + fr) * K + fk;
  const size_t rs = (size_t)128 * K;  // +8 frags = +128 rows

  i32x4 acc[8][4];
#pragma unroll
  for (int i = 0; i < 8; i++)
#pragma unroll
    for (int j = 0; j < 4; j++) acc[i][j] = (i32x4){0, 0, 0, 0};

  i32x4 af[4], bf[4];

#define SB __builtin_amdgcn_sched_barrier(0)
#define BAR __builtin_amdgcn_s_barrier()
#define WAIT_LGKM0 asm volatile("s_waitcnt lgkmcnt(0)" ::: "memory")

#define ISSUE_TILE(t)                                                     \
  do {                                                                    \
    const int b_ = (t) & 3;                                               \
    const int kof_ = (t) * BKK;                                           \
    gld_lds16(ga + kof_,      Abase + ((b_ * 16 + wid) << 10));           \
    gld_lds16(ga + kof_ + rs, Abase + ((b_ * 16 + wid + 8) << 10));       \
    gld_lds16(gb + kof_,      Bbase + ((b_ * 16 + wid) << 10));           \
    gld_lds16(gb + kof_ + rs, Bbase + ((b_ * 16 + wid + 8) << 10));       \
  } while (0)

#define RD_A(i_, mf_) af[i_] = *(const i32x4*)(Abase + (((buf_ * 16) + (mf_)) << 10) + lane * 16)
#define RD_B(j_, nf_) bf[j_] = *(const i32x4*)(Bbase + (((buf_ * 16) + (nf_)) << 10) + lane * 16)

#define MFMA8(IB, JB)                                                          \
  do {                                                                         \
    __builtin_amdgcn_s_setprio(1);                                             \
    _Pragma("unroll") for (int i_ = 0; i_ < 4; i_++)                           \
      _Pragma("unroll") for (int j_ = 0; j_ < 2; j_++)                         \
        acc[(IB) + i_][(JB) + j_] = __builtin_amdgcn_mfma_i32_16x16x64_i8(     \
            af[i_], bf[(JB) + j_], acc[(IB) + i_][(JB) + j_], 0, 0, 0);        \
    __builtin_amdgcn_s_setprio(0);                                             \
  } while (0)

#define TILE(t, DO_ISSUE, VMWAIT)                                              \
  do {                                                                         \
    const int buf_ = (t) & 3;                                                  \
    /* phase 0 */                                                              \
    RD_A(0, wr * 8 + 0); RD_A(1, wr * 8 + 1);                                  \
    RD_A(2, wr * 8 + 2); RD_A(3, wr * 8 + 3);                                  \
    RD_B(0, wc * 4 + 0); RD_B(1, wc * 4 + 1);                                  \
    if (DO_ISSUE) ISSUE_TILE((t) + 3);                                         \
    SB; BAR; SB; WAIT_LGKM0; SB;                                               \
    MFMA8(0, 0);                                                               \
    SB; BAR;                                                                   \
    /* phase 1 */                                                              \
    RD_B(2, wc * 4 + 2); RD_B(3, wc * 4 + 3);                                  \
    SB; BAR; SB; WAIT_LGKM0; SB;                                               \
    MFMA8(0, 2);                                                               \
    SB; BAR;                                                                   \
    /* phase 2 */                                                              \
    RD_A(0, wr * 8 + 4); RD_A(1, wr * 8 + 5);                                  \
    RD_A(2, wr * 8 + 6); RD_A(3, wr * 8 + 7);                                  \
    SB; BAR; SB; WAIT_LGKM0; SB;                                               \
    MFMA8(4, 2);                                                               \
    SB; BAR;                                                                   \
    /* phase 3: counted vmcnt for tile t+1, then barrier -> visible at t+1.P0 */ \
    asm volatile("s_waitcnt " VMWAIT ::: "memory");                            \
    SB; BAR; SB;                                                               \
    MFMA8(4, 0);                                                               \
    SB; BAR;                                                                   \
  } while (0)

  // prologue: 3 tiles in flight, land tile 0
  ISSUE_TILE(0);
  ISSUE_TILE(1);
  ISSUE_TILE(2);
  asm volatile("s_waitcnt vmcnt(8)" ::: "memory");
  SB; BAR; SB;

#pragma unroll 1
  for (int t = 0; t < NKT - 3; ++t) {   // t = 0..12
    TILE(t, 1, "vmcnt(8)");
  }
  TILE(NKT - 3, 0, "vmcnt(4)");
  TILE(NKT - 2, 0, "vmcnt(0)");
  TILE(NKT - 1, 0, "vmcnt(0)");

#undef TILE
#undef MFMA8
#undef RD_A
#undef RD_B
#undef ISSUE_TILE
#undef WAIT_LGKM0
#undef BAR
#undef SB

  // epilogue: C/D layout col = lane&15, row = (lane>>4)*4 + reg
  const int crow0 = m0 + wr * 128;
  const int ccol0 = n0 + wc * 64;
  const int rr = (lane >> 4) * 4;
  const int cc = lane & 15;
#pragma unroll
  for (int j = 0; j < 4; j++) {
    const int col = ccol0 + j * 16 + cc;
    const float bs = bscale[col];
    const float bi = bint[col];
#pragma unroll
    for (int i = 0; i < 8; i++) {
      const int row = crow0 + i * 16 + rr;
#pragma unroll
      for (int r = 0; r < 4; r++) {
        out[(size_t)(row + r) * N + col] = ((float)acc[i][j][r] + bi) * bs;
      }
    }
  }
}

// ---------------- launch ----------------
extern "C" void kernel_launch(void* const* d_in, const int* in_sizes, int n_in,
                              void* d_out, int out_size, void* d_ws, size_t ws_size,
                              hipStream_t stream) {
  const float* hs = (const float*)d_in[0];
  const float* w = (const float*)d_in[1];
  const float* bias = (const float*)d_in[2];
  float* out = (float*)d_out;

  const long long n = (long long)in_sizes[0];     // 50331648
  const int K = K_DIM;                            // 1024
  const int O = in_sizes[2];                      // 1024
  const int M = (int)(n / K);                     // 49152

  // workspace layout (total ~49.3 MB)
  char* ws = (char*)d_ws;
  unsigned int* amax_u = (unsigned int*)ws;                        // 4 B
  float* bscale = (float*)(ws + 256);                              // 4 KB
  float* bint = (float*)(ws + 256 + 4096);                         // 4 KB
  signed char* wq = (signed char*)(ws + 65536);                    // 1 MB
  signed char* xq = (signed char*)(ws + 65536 + 1048576);          // 48 MB

  // opt-in for 128KB dynamic LDS (host-side attribute, not stream-ordered;
  // safe under graph capture, idempotent/deterministic per call)
  hipFuncSetAttribute((const void*)gemm_kernel,
                      hipFuncAttributeMaxDynamicSharedMemorySize, 131072);

  hipMemsetAsync(amax_u, 0, 4, stream);

  const long long n4 = n / 4;
  absmax_kernel<<<2048, 256, 0, stream>>>(hs, amax_u, n4);
  wquant_kernel<<<O, 256, 0, stream>>>(w, bias, amax_u, wq, bscale, bint);
  aquant_kernel<<<2048, 256, 0, stream>>>(hs, amax_u, (unsigned int*)xq, n4);

  const int nblocks = (M / BM) * (O / BN);        // 192 * 4 = 768
  gemm_kernel<<<nblocks, 512, 131072, stream>>>(xq, wq, bscale, bint, out, M, O, K);
}

// Round 5
// 204.691 us; speedup vs baseline: 1.0578x; 1.0578x over previous
//
#include <hip/hip_runtime.h>
#include <stdint.h>

typedef int i32x4 __attribute__((ext_vector_type(4)));

#define K_DIM 1024
#define BM 256
#define BN 256
#define BKK 64
#define NKT (K_DIM / BKK)   // 16

// ---------------- helpers ----------------
__device__ __forceinline__ int quant1(float v, float inv) {
  float t = rintf(v * inv);                 // round half-to-even, matches jnp.round
  t = fminf(fmaxf(t, -128.0f), 127.0f);     // clip(-n-1, n)
  return (int)t;
}

__device__ __forceinline__ void gld_lds16(const signed char* g, signed char* l) {
  typedef const __attribute__((address_space(1))) unsigned int* gp_t;
  typedef __attribute__((address_space(3))) unsigned int* lp_t;
  __builtin_amdgcn_global_load_lds((gp_t)(const void*)g, (lp_t)(void*)l, 16, 0, 0);
}

// ---------------- 1) global absmax over hs ----------------
__global__ void absmax_kernel(const float* __restrict__ x, unsigned int* __restrict__ amax,
                              long long n4) {
  long long i = (long long)blockIdx.x * blockDim.x + threadIdx.x;
  const long long stride = (long long)gridDim.x * blockDim.x;
  const float4* x4 = (const float4*)x;
  float m = 0.0f;
  for (; i < n4; i += stride) {
    float4 v = x4[i];
    m = fmaxf(m, fmaxf(fmaxf(fabsf(v.x), fabsf(v.y)), fmaxf(fabsf(v.z), fabsf(v.w))));
  }
#pragma unroll
  for (int off = 32; off > 0; off >>= 1) m = fmaxf(m, __shfl_down(m, off, 64));
  __shared__ float sm[4];
  const int lane = threadIdx.x & 63, wid = threadIdx.x >> 6;
  if (lane == 0) sm[wid] = m;
  __syncthreads();
  if (threadIdx.x == 0) {
    float b = fmaxf(fmaxf(sm[0], sm[1]), fmaxf(sm[2], sm[3]));
    atomicMax(amax, __float_as_uint(b));   // all values >= 0: uint order == float order
  }
}

// ---------------- 2) per-channel weight quant + bias ----------------
__global__ void wquant_kernel(const float* __restrict__ w, const float* __restrict__ bias,
                              const unsigned int* __restrict__ amax_u,
                              signed char* __restrict__ wq,
                              float* __restrict__ bscale, float* __restrict__ bint) {
  const int o = blockIdx.x;
  const int t = threadIdx.x;
  float4 v = ((const float4*)(w + (size_t)o * K_DIM))[t];
  float m = fmaxf(fmaxf(fabsf(v.x), fabsf(v.y)), fmaxf(fabsf(v.z), fabsf(v.w)));
#pragma unroll
  for (int off = 32; off > 0; off >>= 1) m = fmaxf(m, __shfl_down(m, off, 64));
  __shared__ float sm[4];
  __shared__ float s_scale;
  const int lane = t & 63, wid = t >> 6;
  if (lane == 0) sm[wid] = m;
  __syncthreads();
  if (t == 0) {
    float wm = fmaxf(fmaxf(sm[0], sm[1]), fmaxf(sm[2], sm[3]));
    float wsc = fmaxf(wm, 1e-8f) / 127.0f;
    float asc = fmaxf(__uint_as_float(*amax_u), 1e-8f) / 127.0f;
    float bsc = wsc * asc;
    bscale[o] = bsc;
    bint[o] = rintf(bias[o] / bsc);        // b_int kept as float (unclipped, like ref)
    s_scale = wsc;
  }
  __syncthreads();
  const float inv = 1.0f / s_scale;
  int q0 = quant1(v.x, inv), q1 = quant1(v.y, inv), q2 = quant1(v.z, inv), q3 = quant1(v.w, inv);
  unsigned int p = (unsigned)(q0 & 255) | ((unsigned)(q1 & 255) << 8) |
                   ((unsigned)(q2 & 255) << 16) | ((unsigned)(q3 & 255) << 24);
  ((unsigned int*)wq)[o * 256 + t] = p;
}

// ---------------- 3) activation quant ----------------
__global__ void aquant_kernel(const float* __restrict__ x, const unsigned int* __restrict__ amax_u,
                              unsigned int* __restrict__ q4, long long n4) {
  const float asc = fmaxf(__uint_as_float(*amax_u), 1e-8f) / 127.0f;
  const float inv = 1.0f / asc;
  long long i = (long long)blockIdx.x * blockDim.x + threadIdx.x;
  const long long stride = (long long)gridDim.x * blockDim.x;
  const float4* x4 = (const float4*)x;
  for (; i < n4; i += stride) {
    float4 v = x4[i];
    int q0 = quant1(v.x, inv), q1 = quant1(v.y, inv), q2 = quant1(v.z, inv), q3 = quant1(v.w, inv);
    q4[i] = (unsigned)(q0 & 255) | ((unsigned)(q1 & 255) << 8) |
            ((unsigned)(q2 & 255) << 16) | ((unsigned)(q3 & 255) << 24);
  }
}

// ---------------- 4) int8 GEMM, 8-phase 256x256, LDS-staged coalesced epilogue ----------------
// A[M,K] int8 row-major (x_int), W[N,K] int8 row-major (w_int, B^T)
// out[M,N] f32 = ((int32)A.W^T + b_int[n]) * bscale[n]
//
// K-loop identical to R4 (8-phase counted-vmcnt). NEW: epilogue stages C through
// the (now-dead) 128KB LDS in two 128-row halves so every global store is a
// full-line 1KB-contiguous per-wave float4 row  -> kills the 64B-granule
// write amplification (261MB -> ~202MB) that capped R1/R2/R4 at ~2.2 TB/s.
__global__ __launch_bounds__(512, 2) void gemm_kernel(
    const signed char* __restrict__ A, const signed char* __restrict__ W,
    const float* __restrict__ bscale, const float* __restrict__ bint,
    float* __restrict__ out, int M, int N, int K) {
  extern __shared__ __align__(16) signed char smem[];   // 131072 B
  signed char* Abase = smem;            // [4][16][1024]
  signed char* Bbase = smem + 65536;    // [4][16][1024]

  // bijective XCD swizzle (gridDim.x % 8 == 0)
  const int nwg = gridDim.x;
  const int orig = blockIdx.x;
  const int wgid = (orig & 7) * (nwg >> 3) + (orig >> 3);
  const int nbn = N / BN;
  const int bm = wgid / nbn;
  const int bn = wgid % nbn;
  const int m0 = bm * BM, n0 = bn * BN;

  const int tid = threadIdx.x;
  const int lane = tid & 63;
  const int wid = tid >> 6;          // 8 waves
  const int wr = wid >> 2;           // 2 wave-rows
  const int wc = wid & 3;            // 4 wave-cols

  const int fr = lane & 15;
  const int fk = (lane >> 4) << 4;

  // wave stages A-frags {wid, wid+8}, B-frags {wid, wid+8}
  const signed char* ga = A + (size_t)(m0 + wid * 16 + fr) * K + fk;
  const signed char* gb = W + (size_t)(n0 + wid * 16 + fr) * K + fk;
  const size_t rs = (size_t)128 * K;  // +8 frags = +128 rows

  i32x4 acc[8][4];
#pragma unroll
  for (int i = 0; i < 8; i++)
#pragma unroll
    for (int j = 0; j < 4; j++) acc[i][j] = (i32x4){0, 0, 0, 0};

  i32x4 af[4], bf[4];

#define SB __builtin_amdgcn_sched_barrier(0)
#define BAR __builtin_amdgcn_s_barrier()
#define WAIT_LGKM0 asm volatile("s_waitcnt lgkmcnt(0)" ::: "memory")

#define ISSUE_TILE(t)                                                     \
  do {                                                                    \
    const int b_ = (t) & 3;                                               \
    const int kof_ = (t) * BKK;                                           \
    gld_lds16(ga + kof_,      Abase + ((b_ * 16 + wid) << 10));           \
    gld_lds16(ga + kof_ + rs, Abase + ((b_ * 16 + wid + 8) << 10));       \
    gld_lds16(gb + kof_,      Bbase + ((b_ * 16 + wid) << 10));           \
    gld_lds16(gb + kof_ + rs, Bbase + ((b_ * 16 + wid + 8) << 10));       \
  } while (0)

#define RD_A(i_, mf_) af[i_] = *(const i32x4*)(Abase + (((buf_ * 16) + (mf_)) << 10) + lane * 16)
#define RD_B(j_, nf_) bf[j_] = *(const i32x4*)(Bbase + (((buf_ * 16) + (nf_)) << 10) + lane * 16)

#define MFMA8(IB, JB)                                                          \
  do {                                                                         \
    __builtin_amdgcn_s_setprio(1);                                             \
    _Pragma("unroll") for (int i_ = 0; i_ < 4; i_++)                           \
      _Pragma("unroll") for (int j_ = 0; j_ < 2; j_++)                         \
        acc[(IB) + i_][(JB) + j_] = __builtin_amdgcn_mfma_i32_16x16x64_i8(     \
            af[i_], bf[(JB) + j_], acc[(IB) + i_][(JB) + j_], 0, 0, 0);        \
    __builtin_amdgcn_s_setprio(0);                                             \
  } while (0)

#define TILE(t, DO_ISSUE, VMWAIT)                                              \
  do {                                                                         \
    const int buf_ = (t) & 3;                                                  \
    /* phase 0 */                                                              \
    RD_A(0, wr * 8 + 0); RD_A(1, wr * 8 + 1);                                  \
    RD_A(2, wr * 8 + 2); RD_A(3, wr * 8 + 3);                                  \
    RD_B(0, wc * 4 + 0); RD_B(1, wc * 4 + 1);                                  \
    if (DO_ISSUE) ISSUE_TILE((t) + 3);                                         \
    SB; BAR; SB; WAIT_LGKM0; SB;                                               \
    MFMA8(0, 0);                                                               \
    SB; BAR;                                                                   \
    /* phase 1 */                                                              \
    RD_B(2, wc * 4 + 2); RD_B(3, wc * 4 + 3);                                  \
    SB; BAR; SB; WAIT_LGKM0; SB;                                               \
    MFMA8(0, 2);                                                               \
    SB; BAR;                                                                   \
    /* phase 2 */                                                              \
    RD_A(0, wr * 8 + 4); RD_A(1, wr * 8 + 5);                                  \
    RD_A(2, wr * 8 + 6); RD_A(3, wr * 8 + 7);                                  \
    SB; BAR; SB; WAIT_LGKM0; SB;                                               \
    MFMA8(4, 2);                                                               \
    SB; BAR;                                                                   \
    /* phase 3: counted vmcnt for tile t+1, then barrier -> visible at t+1.P0 */ \
    asm volatile("s_waitcnt " VMWAIT ::: "memory");                            \
    SB; BAR; SB;                                                               \
    MFMA8(4, 0);                                                               \
    SB; BAR;                                                                   \
  } while (0)

  // prologue: 3 tiles in flight, land tile 0
  ISSUE_TILE(0);
  ISSUE_TILE(1);
  ISSUE_TILE(2);
  asm volatile("s_waitcnt vmcnt(8)" ::: "memory");
  SB; BAR; SB;

#pragma unroll 1
  for (int t = 0; t < NKT - 3; ++t) {   // t = 0..12
    TILE(t, 1, "vmcnt(8)");
  }
  TILE(NKT - 3, 0, "vmcnt(4)");
  TILE(NKT - 2, 0, "vmcnt(0)");
  TILE(NKT - 1, 0, "vmcnt(0)");

#undef TILE
#undef MFMA8
#undef RD_A
#undef RD_B
#undef ISSUE_TILE

  // ---- epilogue: LDS-staged, full-line coalesced C writes ----
  // After the K-loop's final barrier all LDS reads are done; reuse the 128KB
  // as float Cst[128][256] (exactly 131072 B), processed in two halves h=0,1
  // (rows m0+h*128 .. +127). C/D frag layout: col = lane&15, row = (lane>>4)*4+reg.
  float* Cst = (float*)smem;
  const int rr = (lane >> 4) * 4;
  const int cc = lane & 15;
#pragma unroll
  for (int h = 0; h < 2; ++h) {
    if (wr == h) {
#pragma unroll
      for (int j = 0; j < 4; j++) {
        const int colL = wc * 64 + j * 16 + cc;     // 0..255 within tile
        const float bs = bscale[n0 + colL];
        const float bi = bint[n0 + colL];
#pragma unroll
        for (int i = 0; i < 8; i++)
#pragma unroll
          for (int r = 0; r < 4; r++)
            Cst[(i * 16 + rr + r) * 256 + colL] = ((float)acc[i][j][r] + bi) * bs;
      }
    }
    WAIT_LGKM0;           // writers: ds_writes done (readers: trivially)
    BAR;                  // all writes visible; no vmcnt drain (stores stream)
    const size_t rowbase = (size_t)(m0 + h * 128) * N + n0;
#pragma unroll
    for (int it = 0; it < 16; ++it) {
      const int r_ = it * 8 + wid;                  // one row per wave per iter
      float4 v = *(const float4*)&Cst[r_ * 256 + lane * 4];   // lane*16B, conflict-free
      *(float4*)&out[rowbase + (size_t)r_ * N + lane * 4] = v; // 1KB contiguous per wave
    }
    WAIT_LGKM0;           // own ds_reads done before h=1 overwrites
    BAR;
  }
#undef WAIT_LGKM0
#undef BAR
#undef SB
}

// ---------------- launch ----------------
extern "C" void kernel_launch(void* const* d_in, const int* in_sizes, int n_in,
                              void* d_out, int out_size, void* d_ws, size_t ws_size,
                              hipStream_t stream) {
  const float* hs = (const float*)d_in[0];
  const float* w = (const float*)d_in[1];
  const float* bias = (const float*)d_in[2];
  float* out = (float*)d_out;

  const long long n = (long long)in_sizes[0];     // 50331648
  const int K = K_DIM;                            // 1024
  const int O = in_sizes[2];                      // 1024
  const int M = (int)(n / K);                     // 49152

  // workspace layout (total ~49.3 MB)
  char* ws = (char*)d_ws;
  unsigned int* amax_u = (unsigned int*)ws;                        // 4 B
  float* bscale = (float*)(ws + 256);                              // 4 KB
  float* bint = (float*)(ws + 256 + 4096);                         // 4 KB
  signed char* wq = (signed char*)(ws + 65536);                    // 1 MB
  signed char* xq = (signed char*)(ws + 65536 + 1048576);          // 48 MB

  // opt-in for 128KB dynamic LDS (host-side attribute, graph-capture-safe)
  hipFuncSetAttribute((const void*)gemm_kernel,
                      hipFuncAttributeMaxDynamicSharedMemorySize, 131072);

  hipMemsetAsync(amax_u, 0, 4, stream);

  const long long n4 = n / 4;
  absmax_kernel<<<2048, 256, 0, stream>>>(hs, amax_u, n4);
  wquant_kernel<<<O, 256, 0, stream>>>(w, bias, amax_u, wq, bscale, bint);
  aquant_kernel<<<2048, 256, 0, stream>>>(hs, amax_u, (unsigned int*)xq, n4);

  const int nblocks = (M / BM) * (O / BN);        // 192 * 4 = 768
  gemm_kernel<<<nblocks, 512, 131072, stream>>>(xq, wq, bscale, bint, out, M, O, K);
}

// Round 6
// 189.716 us; speedup vs baseline: 1.1413x; 1.0789x over previous
//
#include <hip/hip_runtime.h>
#include <stdint.h>

typedef int i32x4 __attribute__((ext_vector_type(4)));

#define K_DIM 1024
#define BM 256
#define BN 256
#define BKK 64
#define NKT (K_DIM / BKK)   // 16

// Fragment-ordered int8 operand layout (shared by aquant/wquant producers and
// the GEMM consumer): fragment (F = row/16, T = k/64) is 1KB stored at offset
// ((F*16)+T)*1024; within it byte b (l=b>>4, j=b&15) holds
// value[row = F*16 + (l&15)][k = T*64 + (l>>4)*16 + j].
// -> GEMM's global_load_lds reads are 1KB FULLY CONTIGUOUS (lane l <-> +l*16),
//    and the LDS image is identical to the previous (verified) lane-linear frag.

// ---------------- helpers ----------------
__device__ __forceinline__ int quant1(float v, float inv) {
  float t = rintf(v * inv);                 // round half-to-even, matches jnp.round
  t = fminf(fmaxf(t, -128.0f), 127.0f);     // clip(-n-1, n)
  return (int)t;
}

__device__ __forceinline__ void gld_lds16(const signed char* g, signed char* l) {
  typedef const __attribute__((address_space(1))) unsigned int* gp_t;
  typedef __attribute__((address_space(3))) unsigned int* lp_t;
  __builtin_amdgcn_global_load_lds((gp_t)(const void*)g, (lp_t)(void*)l, 16, 0, 0);
}

// ---------------- 1) global absmax over hs ----------------
__global__ void absmax_kernel(const float* __restrict__ x, unsigned int* __restrict__ amax,
                              long long n4) {
  long long i = (long long)blockIdx.x * blockDim.x + threadIdx.x;
  const long long stride = (long long)gridDim.x * blockDim.x;
  const float4* x4 = (const float4*)x;
  float m = 0.0f;
  for (; i < n4; i += stride) {
    float4 v = x4[i];
    m = fmaxf(m, fmaxf(fmaxf(fabsf(v.x), fabsf(v.y)), fmaxf(fabsf(v.z), fabsf(v.w))));
  }
#pragma unroll
  for (int off = 32; off > 0; off >>= 1) m = fmaxf(m, __shfl_down(m, off, 64));
  __shared__ float sm[4];
  const int lane = threadIdx.x & 63, wid = threadIdx.x >> 6;
  if (lane == 0) sm[wid] = m;
  __syncthreads();
  if (threadIdx.x == 0) {
    float b = fmaxf(fmaxf(sm[0], sm[1]), fmaxf(sm[2], sm[3]));
    atomicMax(amax, __float_as_uint(b));   // all values >= 0: uint order == float order
  }
}

// ---------------- 2) per-channel weight quant + bias (frag-ordered wq) ----------------
__global__ void wquant_kernel(const float* __restrict__ w, const float* __restrict__ bias,
                              const unsigned int* __restrict__ amax_u,
                              signed char* __restrict__ wq,
                              float* __restrict__ bscale, float* __restrict__ bint) {
  const int o = blockIdx.x;
  const int t = threadIdx.x;          // handles k = 4t .. 4t+3
  float4 v = ((const float4*)(w + (size_t)o * K_DIM))[t];
  float m = fmaxf(fmaxf(fabsf(v.x), fabsf(v.y)), fmaxf(fabsf(v.z), fabsf(v.w)));
#pragma unroll
  for (int off = 32; off > 0; off >>= 1) m = fmaxf(m, __shfl_down(m, off, 64));
  __shared__ float sm[4];
  __shared__ float s_scale;
  const int lane = t & 63, wid = t >> 6;
  if (lane == 0) sm[wid] = m;
  __syncthreads();
  if (t == 0) {
    float wm = fmaxf(fmaxf(sm[0], sm[1]), fmaxf(sm[2], sm[3]));
    float wsc = fmaxf(wm, 1e-8f) / 127.0f;
    float asc = fmaxf(__uint_as_float(*amax_u), 1e-8f) / 127.0f;
    float bsc = wsc * asc;
    bscale[o] = bsc;
    bint[o] = rintf(bias[o] / bsc);        // b_int kept as float (unclipped, like ref)
    s_scale = wsc;
  }
  __syncthreads();
  const float inv = 1.0f / s_scale;
  int q0 = quant1(v.x, inv), q1 = quant1(v.y, inv), q2 = quant1(v.z, inv), q3 = quant1(v.w, inv);
  unsigned int p = (unsigned)(q0 & 255) | ((unsigned)(q1 & 255) << 8) |
                   ((unsigned)(q2 & 255) << 16) | ((unsigned)(q3 & 255) << 24);
  // frag-ordered destination: F=o>>4, T=k>>6=t>>4, l=((k>>4)&3)*16 | (o&15), j=k&15
  const int F = o >> 4, T = t >> 4;
  const int l = (((t >> 2) & 3) << 4) | (o & 15);
  const int j = (t << 2) & 15;
  *(unsigned int*)(wq + (((size_t)F << 14) + (T << 10) + (l << 4) + j)) = p;
}

// ---------------- 3) activation quant (frag-ordered xq) ----------------
// chunk c <-> (F = c>>10, T = (c>>6)&15, l = c&63); dst offset = c*16 (linear!).
// src: 16 consecutive floats at row = F*16+(l&15), k0 = T*64+(l>>4)*16.
__global__ void aquant_kernel(const float* __restrict__ x, const unsigned int* __restrict__ amax_u,
                              uint4* __restrict__ q16, int nchunk) {
  const float asc = fmaxf(__uint_as_float(*amax_u), 1e-8f) / 127.0f;
  const float inv = 1.0f / asc;
  int c = blockIdx.x * blockDim.x + threadIdx.x;
  const int stride = gridDim.x * blockDim.x;
  for (; c < nchunk; c += stride) {
    const int l = c & 63, T = (c >> 6) & 15, F = c >> 10;
    const size_t src = (((size_t)(F << 4) + (l & 15)) << 10) + (T << 6) + ((l >> 4) << 4);
    const float4* s4 = (const float4*)(x + src);
    unsigned int r[4];
#pragma unroll
    for (int q = 0; q < 4; q++) {
      float4 v = s4[q];
      int q0 = quant1(v.x, inv), q1 = quant1(v.y, inv), q2 = quant1(v.z, inv), q3 = quant1(v.w, inv);
      r[q] = (unsigned)(q0 & 255) | ((unsigned)(q1 & 255) << 8) |
             ((unsigned)(q2 & 255) << 16) | ((unsigned)(q3 & 255) << 24);
    }
    q16[c] = make_uint4(r[0], r[1], r[2], r[3]);
  }
}

// ---------------- 4) int8 GEMM, 8-phase 256x256, contiguous frag-ordered staging ----------------
// A,W in frag-ordered layout (see top). out[M,N] f32 = ((i32)A.W^T + b_int[n])*bscale[n].
// K-loop and LDS-staged epilogue identical to R5; ONLY the global staging
// addresses changed: each gld_lds now reads 1KB contiguous.
__global__ __launch_bounds__(512, 2) void gemm_kernel(
    const signed char* __restrict__ A, const signed char* __restrict__ W,
    const float* __restrict__ bscale, const float* __restrict__ bint,
    float* __restrict__ out, int M, int N, int K) {
  extern __shared__ __align__(16) signed char smem[];   // 131072 B
  signed char* Abase = smem;            // [4][16][1024]
  signed char* Bbase = smem + 65536;    // [4][16][1024]

  // bijective XCD swizzle (gridDim.x % 8 == 0)
  const int nwg = gridDim.x;
  const int orig = blockIdx.x;
  const int wgid = (orig & 7) * (nwg >> 3) + (orig >> 3);
  const int nbn = N / BN;
  const int bm = wgid / nbn;
  const int bn = wgid % nbn;
  const int m0 = bm * BM, n0 = bn * BN;

  const int tid = threadIdx.x;
  const int lane = tid & 63;
  const int wid = tid >> 6;          // 8 waves
  const int wr = wid >> 2;           // 2 wave-rows
  const int wc = wid & 3;            // 4 wave-cols

  // frag-ordered global bases: wave stages A-frags {(m0/16)+wid, +8}, B likewise.
  // frag (F,t) at (F<<14)+(t<<10); per-lane +lane*16 -> 1KB contiguous per gld.
  const signed char* gaf = A + (((size_t)(m0 >> 4) + wid) << 14) + (lane << 4);
  const signed char* gbf = W + (((size_t)(n0 >> 4) + wid) << 14) + (lane << 4);
  const size_t fs8 = (size_t)8 << 14;   // +8 frags

  i32x4 acc[8][4];
#pragma unroll
  for (int i = 0; i < 8; i++)
#pragma unroll
    for (int j = 0; j < 4; j++) acc[i][j] = (i32x4){0, 0, 0, 0};

  i32x4 af[4], bf[4];

#define SB __builtin_amdgcn_sched_barrier(0)
#define BAR __builtin_amdgcn_s_barrier()
#define WAIT_LGKM0 asm volatile("s_waitcnt lgkmcnt(0)" ::: "memory")

#define ISSUE_TILE(t)                                                     \
  do {                                                                    \
    const int b_ = (t) & 3;                                               \
    const int kof_ = (t) << 10;                                           \
    gld_lds16(gaf + kof_,       Abase + ((b_ * 16 + wid) << 10));         \
    gld_lds16(gaf + fs8 + kof_, Abase + ((b_ * 16 + wid + 8) << 10));     \
    gld_lds16(gbf + kof_,       Bbase + ((b_ * 16 + wid) << 10));         \
    gld_lds16(gbf + fs8 + kof_, Bbase + ((b_ * 16 + wid + 8) << 10));     \
  } while (0)

#define RD_A(i_, mf_) af[i_] = *(const i32x4*)(Abase + (((buf_ * 16) + (mf_)) << 10) + lane * 16)
#define RD_B(j_, nf_) bf[j_] = *(const i32x4*)(Bbase + (((buf_ * 16) + (nf_)) << 10) + lane * 16)

#define MFMA8(IB, JB)                                                          \
  do {                                                                         \
    __builtin_amdgcn_s_setprio(1);                                             \
    _Pragma("unroll") for (int i_ = 0; i_ < 4; i_++)                           \
      _Pragma("unroll") for (int j_ = 0; j_ < 2; j_++)                         \
        acc[(IB) + i_][(JB) + j_] = __builtin_amdgcn_mfma_i32_16x16x64_i8(     \
            af[i_], bf[(JB) + j_], acc[(IB) + i_][(JB) + j_], 0, 0, 0);        \
    __builtin_amdgcn_s_setprio(0);                                             \
  } while (0)

#define TILE(t, DO_ISSUE, VMWAIT)                                              \
  do {                                                                         \
    const int buf_ = (t) & 3;                                                  \
    /* phase 0 */                                                              \
    RD_A(0, wr * 8 + 0); RD_A(1, wr * 8 + 1);                                  \
    RD_A(2, wr * 8 + 2); RD_A(3, wr * 8 + 3);                                  \
    RD_B(0, wc * 4 + 0); RD_B(1, wc * 4 + 1);                                  \
    if (DO_ISSUE) ISSUE_TILE((t) + 3);                                         \
    SB; BAR; SB; WAIT_LGKM0; SB;                                               \
    MFMA8(0, 0);                                                               \
    SB; BAR;                                                                   \
    /* phase 1 */                                                              \
    RD_B(2, wc * 4 + 2); RD_B(3, wc * 4 + 3);                                  \
    SB; BAR; SB; WAIT_LGKM0; SB;                                               \
    MFMA8(0, 2);                                                               \
    SB; BAR;                                                                   \
    /* phase 2 */                                                              \
    RD_A(0, wr * 8 + 4); RD_A(1, wr * 8 + 5);                                  \
    RD_A(2, wr * 8 + 6); RD_A(3, wr * 8 + 7);                                  \
    SB; BAR; SB; WAIT_LGKM0; SB;                                               \
    MFMA8(4, 2);                                                               \
    SB; BAR;                                                                   \
    /* phase 3: counted vmcnt for tile t+1, then barrier -> visible at t+1.P0 */ \
    asm volatile("s_waitcnt " VMWAIT ::: "memory");                            \
    SB; BAR; SB;                                                               \
    MFMA8(4, 0);                                                               \
    SB; BAR;                                                                   \
  } while (0)

  // prologue: 3 tiles in flight, land tile 0
  ISSUE_TILE(0);
  ISSUE_TILE(1);
  ISSUE_TILE(2);
  asm volatile("s_waitcnt vmcnt(8)" ::: "memory");
  SB; BAR; SB;

#pragma unroll 1
  for (int t = 0; t < NKT - 3; ++t) {   // t = 0..12
    TILE(t, 1, "vmcnt(8)");
  }
  TILE(NKT - 3, 0, "vmcnt(4)");
  TILE(NKT - 2, 0, "vmcnt(0)");
  TILE(NKT - 1, 0, "vmcnt(0)");

#undef TILE
#undef MFMA8
#undef RD_A
#undef RD_B
#undef ISSUE_TILE

  // ---- epilogue: LDS-staged, full-line coalesced C writes (unchanged from R5) ----
  float* Cst = (float*)smem;
  const int rr = (lane >> 4) * 4;
  const int cc = lane & 15;
#pragma unroll
  for (int h = 0; h < 2; ++h) {
    if (wr == h) {
#pragma unroll
      for (int j = 0; j < 4; j++) {
        const int colL = wc * 64 + j * 16 + cc;     // 0..255 within tile
        const float bs = bscale[n0 + colL];
        const float bi = bint[n0 + colL];
#pragma unroll
        for (int i = 0; i < 8; i++)
#pragma unroll
          for (int r = 0; r < 4; r++)
            Cst[(i * 16 + rr + r) * 256 + colL] = ((float)acc[i][j][r] + bi) * bs;
      }
    }
    WAIT_LGKM0;
    BAR;
    const size_t rowbase = (size_t)(m0 + h * 128) * N + n0;
#pragma unroll
    for (int it = 0; it < 16; ++it) {
      const int r_ = it * 8 + wid;                  // one row per wave per iter
      float4 v = *(const float4*)&Cst[r_ * 256 + lane * 4];
      *(float4*)&out[rowbase + (size_t)r_ * N + lane * 4] = v;
    }
    WAIT_LGKM0;
    BAR;
  }
#undef WAIT_LGKM0
#undef BAR
#undef SB
}

// ---------------- launch ----------------
extern "C" void kernel_launch(void* const* d_in, const int* in_sizes, int n_in,
                              void* d_out, int out_size, void* d_ws, size_t ws_size,
                              hipStream_t stream) {
  const float* hs = (const float*)d_in[0];
  const float* w = (const float*)d_in[1];
  const float* bias = (const float*)d_in[2];
  float* out = (float*)d_out;

  const long long n = (long long)in_sizes[0];     // 50331648
  const int K = K_DIM;                            // 1024
  const int O = in_sizes[2];                      // 1024
  const int M = (int)(n / K);                     // 49152

  // workspace layout (total ~49.3 MB)
  char* ws = (char*)d_ws;
  unsigned int* amax_u = (unsigned int*)ws;                        // 4 B
  float* bscale = (float*)(ws + 256);                              // 4 KB
  float* bint = (float*)(ws + 256 + 4096);                         // 4 KB
  signed char* wq = (signed char*)(ws + 65536);                    // 1 MB (frag-ordered)
  signed char* xq = (signed char*)(ws + 65536 + 1048576);          // 48 MB (frag-ordered)

  // opt-in for 128KB dynamic LDS (host-side attribute, graph-capture-safe)
  hipFuncSetAttribute((const void*)gemm_kernel,
                      hipFuncAttributeMaxDynamicSharedMemorySize, 131072);

  hipMemsetAsync(amax_u, 0, 4, stream);

  const long long n4 = n / 4;
  absmax_kernel<<<2048, 256, 0, stream>>>(hs, amax_u, n4);
  wquant_kernel<<<O, 256, 0, stream>>>(w, bias, amax_u, wq, bscale, bint);
  const int nchunk = (int)(n / 16);               // 3145728 16B chunks
  aquant_kernel<<<2048, 256, 0, stream>>>(hs, amax_u, (uint4*)xq, nchunk);

  const int nblocks = (M / BM) * (O / BN);        // 192 * 4 = 768
  gemm_kernel<<<nblocks, 512, 131072, stream>>>(xq, wq, bscale, bint, out, M, O, K);
}

// Round 7
// 186.424 us; speedup vs baseline: 1.1614x; 1.0177x over previous
//
#include <hip/hip_runtime.h>
#include <stdint.h>

typedef int i32x4 __attribute__((ext_vector_type(4)));

#define K_DIM 1024
#define BM 256
#define BN 256
#define BKK 64
#define NKT (K_DIM / BKK)   // 16

// Fragment-ordered int8 operand layout (shared by aquant/wquant producers and
// the GEMM consumer): fragment (F = row/16, T = k/64) is 1KB stored at offset
// ((F*16)+T)*1024; within it byte b (l=b>>4, j=b&15) holds
// value[row = F*16 + (l&15)][k = T*64 + (l>>4)*16 + j].
// -> GEMM's global_load_lds reads are 1KB FULLY CONTIGUOUS (lane l <-> +l*16),
//    and the LDS image is identical to the verified lane-linear fragment.

// ---------------- helpers ----------------
__device__ __forceinline__ int quant1(float v, float inv) {
  float t = rintf(v * inv);                 // round half-to-even, matches jnp.round
  t = fminf(fmaxf(t, -128.0f), 127.0f);     // clip(-n-1, n)
  return (int)t;
}

__device__ __forceinline__ void gld_lds16(const signed char* g, signed char* l) {
  typedef const __attribute__((address_space(1))) unsigned int* gp_t;
  typedef __attribute__((address_space(3))) unsigned int* lp_t;
  __builtin_amdgcn_global_load_lds((gp_t)(const void*)g, (lp_t)(void*)l, 16, 0, 0);
}

// ---------------- 1) global absmax over hs ----------------
__global__ void absmax_kernel(const float* __restrict__ x, unsigned int* __restrict__ amax,
                              long long n4) {
  long long i = (long long)blockIdx.x * blockDim.x + threadIdx.x;
  const long long stride = (long long)gridDim.x * blockDim.x;
  const float4* x4 = (const float4*)x;
  float m = 0.0f;
  for (; i < n4; i += stride) {
    float4 v = x4[i];
    m = fmaxf(m, fmaxf(fmaxf(fabsf(v.x), fabsf(v.y)), fmaxf(fabsf(v.z), fabsf(v.w))));
  }
#pragma unroll
  for (int off = 32; off > 0; off >>= 1) m = fmaxf(m, __shfl_down(m, off, 64));
  __shared__ float sm[4];
  const int lane = threadIdx.x & 63, wid = threadIdx.x >> 6;
  if (lane == 0) sm[wid] = m;
  __syncthreads();
  if (threadIdx.x == 0) {
    float b = fmaxf(fmaxf(sm[0], sm[1]), fmaxf(sm[2], sm[3]));
    atomicMax(amax, __float_as_uint(b));   // all values >= 0: uint order == float order
  }
}

// ---------------- 2) per-channel weight quant + bias (frag-ordered wq) ----------------
__global__ void wquant_kernel(const float* __restrict__ w, const float* __restrict__ bias,
                              const unsigned int* __restrict__ amax_u,
                              signed char* __restrict__ wq,
                              float* __restrict__ bscale, float* __restrict__ bint) {
  const int o = blockIdx.x;
  const int t = threadIdx.x;          // handles k = 4t .. 4t+3
  float4 v = ((const float4*)(w + (size_t)o * K_DIM))[t];
  float m = fmaxf(fmaxf(fabsf(v.x), fabsf(v.y)), fmaxf(fabsf(v.z), fabsf(v.w)));
#pragma unroll
  for (int off = 32; off > 0; off >>= 1) m = fmaxf(m, __shfl_down(m, off, 64));
  __shared__ float sm[4];
  __shared__ float s_scale;
  const int lane = t & 63, wid = t >> 6;
  if (lane == 0) sm[wid] = m;
  __syncthreads();
  if (t == 0) {
    float wm = fmaxf(fmaxf(sm[0], sm[1]), fmaxf(sm[2], sm[3]));
    float wsc = fmaxf(wm, 1e-8f) / 127.0f;
    float asc = fmaxf(__uint_as_float(*amax_u), 1e-8f) / 127.0f;
    float bsc = wsc * asc;
    bscale[o] = bsc;
    bint[o] = rintf(bias[o] / bsc);        // b_int kept as float (unclipped, like ref)
    s_scale = wsc;
  }
  __syncthreads();
  const float inv = 1.0f / s_scale;
  int q0 = quant1(v.x, inv), q1 = quant1(v.y, inv), q2 = quant1(v.z, inv), q3 = quant1(v.w, inv);
  unsigned int p = (unsigned)(q0 & 255) | ((unsigned)(q1 & 255) << 8) |
                   ((unsigned)(q2 & 255) << 16) | ((unsigned)(q3 & 255) << 24);
  // frag-ordered destination: F=o>>4, T=k>>6=t>>4, l=((k>>4)&3)*16 | (o&15), j=k&15
  const int F = o >> 4, T = t >> 4;
  const int l = (((t >> 2) & 3) << 4) | (o & 15);
  const int j = (t << 2) & 15;
  *(unsigned int*)(wq + (((size_t)F << 14) + (T << 10) + (l << 4) + j)) = p;
}

// ---------------- 3) activation quant (frag-ordered xq) ----------------
// chunk c <-> (F = c>>10, T = (c>>6)&15, l = c&63); dst offset = c*16 (linear!).
// src: 16 consecutive floats at row = F*16+(l&15), k0 = T*64+(l>>4)*16.
__global__ void aquant_kernel(const float* __restrict__ x, const unsigned int* __restrict__ amax_u,
                              uint4* __restrict__ q16, int nchunk) {
  const float asc = fmaxf(__uint_as_float(*amax_u), 1e-8f) / 127.0f;
  const float inv = 1.0f / asc;
  int c = blockIdx.x * blockDim.x + threadIdx.x;
  const int stride = gridDim.x * blockDim.x;
  for (; c < nchunk; c += stride) {
    const int l = c & 63, T = (c >> 6) & 15, F = c >> 10;
    const size_t src = (((size_t)(F << 4) + (l & 15)) << 10) + (T << 6) + ((l >> 4) << 4);
    const float4* s4 = (const float4*)(x + src);
    unsigned int r[4];
#pragma unroll
    for (int q = 0; q < 4; q++) {
      float4 v = s4[q];
      int q0 = quant1(v.x, inv), q1 = quant1(v.y, inv), q2 = quant1(v.z, inv), q3 = quant1(v.w, inv);
      r[q] = (unsigned)(q0 & 255) | ((unsigned)(q1 & 255) << 8) |
             ((unsigned)(q2 & 255) << 16) | ((unsigned)(q3 & 255) << 24);
    }
    q16[c] = make_uint4(r[0], r[1], r[2], r[3]);
  }
}

// ---------------- 4) int8 GEMM: 1-barrier-per-K-tile, 32 MFMA per sync ----------------
// A,W frag-ordered (see top). out[M,N] f32 = ((i32)A.W^T + b_int[n])*bscale[n].
// 512 thr = 8 waves (2Mx4N), wave tile 128x64, acc[8][4] i32x4.
// Per K-tile: {ISSUE tile t+3 (4x gld_lds, 1KB contiguous each) ; 12x ds_read_b128 ;
//   2x 16-MFMA setprio clusters (compiler emits fine-grained lgkm waits) ;
//   counted vmcnt(8) ; ONE s_barrier}.  Intra-tile LDS hazards are read-read;
//   the only WAR (ISSUE(t+3) overwrites buf (t-1)&3) is fenced by the tile barrier.
//   Waves drift within a tile -> 2 waves/SIMD overlap ds_read with MFMA.
__global__ __launch_bounds__(512, 2) void gemm_kernel(
    const signed char* __restrict__ A, const signed char* __restrict__ W,
    const float* __restrict__ bscale, const float* __restrict__ bint,
    float* __restrict__ out, int M, int N, int K) {
  extern __shared__ __align__(16) signed char smem[];   // 131072 B
  signed char* Abase = smem;            // [4][16][1024]
  signed char* Bbase = smem + 65536;    // [4][16][1024]

  // bijective XCD swizzle (gridDim.x % 8 == 0)
  const int nwg = gridDim.x;
  const int orig = blockIdx.x;
  const int wgid = (orig & 7) * (nwg >> 3) + (orig >> 3);
  const int nbn = N / BN;
  const int bm = wgid / nbn;
  const int bn = wgid % nbn;
  const int m0 = bm * BM, n0 = bn * BN;

  const int tid = threadIdx.x;
  const int lane = tid & 63;
  const int wid = tid >> 6;          // 8 waves
  const int wr = wid >> 2;           // 2 wave-rows
  const int wc = wid & 3;            // 4 wave-cols

  // frag-ordered global bases: wave stages A-frags {(m0/16)+wid, +8}, B likewise.
  const signed char* gaf = A + (((size_t)(m0 >> 4) + wid) << 14) + (lane << 4);
  const signed char* gbf = W + (((size_t)(n0 >> 4) + wid) << 14) + (lane << 4);
  const size_t fs8 = (size_t)8 << 14;   // +8 frags

  i32x4 acc[8][4];
#pragma unroll
  for (int i = 0; i < 8; i++)
#pragma unroll
    for (int j = 0; j < 4; j++) acc[i][j] = (i32x4){0, 0, 0, 0};

  i32x4 af[8], bf[4];

#define SB __builtin_amdgcn_sched_barrier(0)
#define BAR __builtin_amdgcn_s_barrier()
#define WAIT_LGKM0 asm volatile("s_waitcnt lgkmcnt(0)" ::: "memory")

#define ISSUE_TILE(t)                                                     \
  do {                                                                    \
    const int b_ = (t) & 3;                                               \
    const int kof_ = (t) << 10;                                           \
    gld_lds16(gaf + kof_,       Abase + ((b_ * 16 + wid) << 10));         \
    gld_lds16(gaf + fs8 + kof_, Abase + ((b_ * 16 + wid + 8) << 10));     \
    gld_lds16(gbf + kof_,       Bbase + ((b_ * 16 + wid) << 10));         \
    gld_lds16(gbf + fs8 + kof_, Bbase + ((b_ * 16 + wid + 8) << 10));     \
  } while (0)

#define RD_A(i_, mf_) af[i_] = *(const i32x4*)(Abase + (((buf_ * 16) + (mf_)) << 10) + lane * 16)
#define RD_B(j_, nf_) bf[j_] = *(const i32x4*)(Bbase + (((buf_ * 16) + (nf_)) << 10) + lane * 16)

#define MFMA16(IB)                                                             \
  do {                                                                         \
    __builtin_amdgcn_s_setprio(1);                                             \
    _Pragma("unroll") for (int i_ = 0; i_ < 4; i_++)                           \
      _Pragma("unroll") for (int j_ = 0; j_ < 4; j_++)                         \
        acc[(IB) + i_][j_] = __builtin_amdgcn_mfma_i32_16x16x64_i8(            \
            af[(IB) + i_], bf[j_], acc[(IB) + i_][j_], 0, 0, 0);               \
    __builtin_amdgcn_s_setprio(0);                                             \
  } while (0)

// One K-tile: issue prefetch, 12 reads, 32 MFMA, counted vmcnt, ONE barrier.
#define TILE(t, DO_ISSUE, VMW, DO_VM)                                          \
  do {                                                                         \
    const int buf_ = (t) & 3;                                                  \
    if (DO_ISSUE) ISSUE_TILE((t) + 3);                                         \
    RD_A(0, wr * 8 + 0); RD_A(1, wr * 8 + 1);                                  \
    RD_A(2, wr * 8 + 2); RD_A(3, wr * 8 + 3);                                  \
    RD_B(0, wc * 4 + 0); RD_B(1, wc * 4 + 1);                                  \
    RD_B(2, wc * 4 + 2); RD_B(3, wc * 4 + 3);                                  \
    RD_A(4, wr * 8 + 4); RD_A(5, wr * 8 + 5);                                  \
    RD_A(6, wr * 8 + 6); RD_A(7, wr * 8 + 7);                                  \
    MFMA16(0);                                                                 \
    MFMA16(4);                                                                 \
    if (DO_VM) { asm volatile("s_waitcnt " VMW ::: "memory"); }                \
    SB; BAR; SB;                                                               \
  } while (0)

  // prologue: 3 tiles in flight, land tile 0 (12 outstanding -> 8)
  ISSUE_TILE(0);
  ISSUE_TILE(1);
  ISSUE_TILE(2);
  asm volatile("s_waitcnt vmcnt(8)" ::: "memory");
  SB; BAR; SB;

#pragma unroll 1
  for (int t = 0; t < NKT - 3; ++t) {   // t = 0..12
    TILE(t, 1, "vmcnt(8)", 1);
  }
  TILE(NKT - 3, 0, "vmcnt(4)", 1);      // t=13: tiles<=14 landed
  TILE(NKT - 2, 0, "vmcnt(0)", 1);      // t=14: all landed
  TILE(NKT - 1, 0, "", 0);              // t=15: nothing outstanding

#undef TILE
#undef MFMA16
#undef RD_A
#undef RD_B
#undef ISSUE_TILE

  // ---- epilogue: LDS-staged, full-line coalesced C writes (unchanged from R5) ----
  float* Cst = (float*)smem;
  const int rr = (lane >> 4) * 4;
  const int cc = lane & 15;
#pragma unroll
  for (int h = 0; h < 2; ++h) {
    if (wr == h) {
#pragma unroll
      for (int j = 0; j < 4; j++) {
        const int colL = wc * 64 + j * 16 + cc;     // 0..255 within tile
        const float bs = bscale[n0 + colL];
        const float bi = bint[n0 + colL];
#pragma unroll
        for (int i = 0; i < 8; i++)
#pragma unroll
          for (int r = 0; r < 4; r++)
            Cst[(i * 16 + rr + r) * 256 + colL] = ((float)acc[i][j][r] + bi) * bs;
      }
    }
    WAIT_LGKM0;
    BAR;
    const size_t rowbase = (size_t)(m0 + h * 128) * N + n0;
#pragma unroll
    for (int it = 0; it < 16; ++it) {
      const int r_ = it * 8 + wid;                  // one row per wave per iter
      float4 v = *(const float4*)&Cst[r_ * 256 + lane * 4];
      *(float4*)&out[rowbase + (size_t)r_ * N + lane * 4] = v;
    }
    WAIT_LGKM0;
    BAR;
  }
#undef WAIT_LGKM0
#undef BAR
#undef SB
}

// ---------------- launch ----------------
extern "C" void kernel_launch(void* const* d_in, const int* in_sizes, int n_in,
                              void* d_out, int out_size, void* d_ws, size_t ws_size,
                              hipStream_t stream) {
  const float* hs = (const float*)d_in[0];
  const float* w = (const float*)d_in[1];
  const float* bias = (const float*)d_in[2];
  float* out = (float*)d_out;

  const long long n = (long long)in_sizes[0];     // 50331648
  const int K = K_DIM;                            // 1024
  const int O = in_sizes[2];                      // 1024
  const int M = (int)(n / K);                     // 49152

  // workspace layout (total ~49.3 MB)
  char* ws = (char*)d_ws;
  unsigned int* amax_u = (unsigned int*)ws;                        // 4 B
  float* bscale = (float*)(ws + 256);                              // 4 KB
  float* bint = (float*)(ws + 256 + 4096);                         // 4 KB
  signed char* wq = (signed char*)(ws + 65536);                    // 1 MB (frag-ordered)
  signed char* xq = (signed char*)(ws + 65536 + 1048576);          // 48 MB (frag-ordered)

  // opt-in for 128KB dynamic LDS (host-side attribute, graph-capture-safe)
  hipFuncSetAttribute((const void*)gemm_kernel,
                      hipFuncAttributeMaxDynamicSharedMemorySize, 131072);

  hipMemsetAsync(amax_u, 0, 4, stream);

  const long long n4 = n / 4;
  absmax_kernel<<<2048, 256, 0, stream>>>(hs, amax_u, n4);
  wquant_kernel<<<O, 256, 0, stream>>>(w, bias, amax_u, wq, bscale, bint);
  const int nchunk = (int)(n / 16);               // 3145728 16B chunks
  aquant_kernel<<<2048, 256, 0, stream>>>(hs, amax_u, (uint4*)xq, nchunk);

  const int nblocks = (M / BM) * (O / BN);        // 192 * 4 = 768
  gemm_kernel<<<nblocks, 512, 131072, stream>>>(xq, wq, bscale, bint, out, M, O, K);
}